// Round 3
// baseline (2498.449 us; speedup 1.0000x reference)
//
#include <hip/hip_runtime.h>

// ---------------------------------------------------------------------------
// DenseGATLayer: LN1 -> QKV proj -> adj-masked MHA -> WO proj + residual
//                -> LN2 -> GELU FFN -> residual
// B=32 N=512 D=768 H=12 HD=64. Compute: bf16 MFMA, fp32 accumulation.
// Input dtype (bf16 vs fp32) is sniffed at runtime from x's bit patterns;
// all raw-input loads and the final store go through flag-selected paths.
// Workspace: ~114 MiB with aliasing (attn out in-place over Q, FFN hidden
// chunk over K, etc). Resubmission of round-2 source (container infra fail).
// ---------------------------------------------------------------------------

#define Bn 32
#define Nn 512
#define Dn 768
#define Hn 12
#define HDn 64
#define Mn (Bn * Nn)      // 16384 rows
#define DFn 3072          // FFN hidden
#define MCHUNK 4096       // FFN M-chunk rows

typedef unsigned short u16;
typedef short bf16x8 __attribute__((ext_vector_type(8)));      // 8 bf16 (4 VGPR)
typedef float f32x4 __attribute__((ext_vector_type(4)));       // MFMA acc
typedef unsigned short u16x8 __attribute__((ext_vector_type(8)));

__device__ __forceinline__ float b2f(u16 u) {
    return __uint_as_float(((unsigned int)u) << 16);
}
__device__ __forceinline__ u16 f2b(float f) {
    unsigned int u = __float_as_uint(f);
    u += 0x7fffu + ((u >> 16) & 1u);   // RNE
    return (u16)(u >> 16);
}
// flag-selected raw-input load: f=1 -> fp32 array, f=0 -> bf16 array
__device__ __forceinline__ float loadDyn(const void* p, size_t i, int f) {
    return f ? ((const float*)p)[i] : b2f(((const u16*)p)[i]);
}
__device__ __forceinline__ float gelu_exact(float x) {
    return 0.5f * x * (1.0f + erff(x * 0.70710678118654752f));
}
__device__ __forceinline__ float waveRedSum(float v) {
#pragma unroll
    for (int off = 32; off > 0; off >>= 1) v += __shfl_xor(v, off, 64);
    return v;
}

// ---------------------------------------------------------------------------
// Dtype sniffer: bf16 NaN/Inf bit patterns ((u&0x7F80)==0x7F80) never occur
// in genuine bf16 N(0,1)-scale data, but appear at ~1/256 rate in the low
// mantissa halves of fp32 data viewed as u16 (~256 hits in 128K words).
// flag=1 => inputs are fp32.
// ---------------------------------------------------------------------------
__global__ __launch_bounds__(256) void sniff_k(const u16* __restrict__ x,
                                               int* __restrict__ flag) {
    __shared__ int tot;
    if (threadIdx.x == 0) tot = 0;
    __syncthreads();
    int cnt = 0;
    for (int i = threadIdx.x; i < 131072; i += 256) {
        u16 u = x[i];
        cnt += ((u & 0x7F80) == 0x7F80) ? 1 : 0;
    }
    atomicAdd(&tot, cnt);
    __syncthreads();
    if (threadIdx.x == 0) *flag = (tot > 32) ? 1 : 0;
}

// ---------------------------------------------------------------------------
// Transpose raw weight -> canonical bf16: out[c][r] = in[r][c]
// ---------------------------------------------------------------------------
__global__ __launch_bounds__(256) void transpose_k(
    const void* __restrict__ in, u16* __restrict__ out, int R, int C,
    const int* __restrict__ flagp) {
    const int f = *flagp;
    __shared__ u16 tile[32][33];
    int c0 = blockIdx.x * 32, r0 = blockIdx.y * 32;
    int tx = threadIdx.x, ty = threadIdx.y;  // 32 x 8
#pragma unroll
    for (int i = 0; i < 32; i += 8)
        tile[ty + i][tx] = f2b(loadDyn(in, (size_t)(r0 + ty + i) * C + c0 + tx, f));
    __syncthreads();
#pragma unroll
    for (int i = 0; i < 32; i += 8)
        out[(size_t)(c0 + ty + i) * R + r0 + tx] = tile[tx][ty + i];
}

// ---------------------------------------------------------------------------
// LayerNorm over D=768, one block (256 thr) per row. XDYN: x is raw input
// (flag-selected dtype) vs canonical bf16 ws buffer. g/b are always raw.
// ---------------------------------------------------------------------------
template <int XDYN>
__global__ __launch_bounds__(256) void ln_k(
    const void* __restrict__ x, const void* __restrict__ g,
    const void* __restrict__ b, u16* __restrict__ y,
    const int* __restrict__ flagp) {
    const int f = *flagp;
    const int row = blockIdx.x;
    const int tid = threadIdx.x;
    const size_t base = (size_t)row * Dn;
    float v[3];
#pragma unroll
    for (int i = 0; i < 3; i++) {
        size_t idx = base + tid + i * 256;
        v[i] = XDYN ? loadDyn(x, idx, f) : b2f(((const u16*)x)[idx]);
    }
    __shared__ float red[8];
    float s = waveRedSum(v[0] + v[1] + v[2]);
    if ((tid & 63) == 0) red[tid >> 6] = s;
    __syncthreads();
    float mu = (red[0] + red[1] + red[2] + red[3]) * (1.0f / Dn);
    float d2 = 0.f;
#pragma unroll
    for (int i = 0; i < 3; i++) { float d = v[i] - mu; d2 += d * d; }
    d2 = waveRedSum(d2);
    if ((tid & 63) == 0) red[4 + (tid >> 6)] = d2;
    __syncthreads();
    float var = (red[4] + red[5] + red[6] + red[7]) * (1.0f / Dn);
    float rstd = rsqrtf(var + 1e-5f);
#pragma unroll
    for (int i = 0; i < 3; i++) {
        int c = tid + i * 256;
        float o = (v[i] - mu) * rstd * loadDyn(g, c, f) + loadDyn(b, c, f);
        y[base + c] = f2b(o);
    }
}

// ---------------------------------------------------------------------------
// GEMM: C[moff+M rows][N] = epi( A[M][K] @ Bt[N][K]^T + bias[N] (+res) )
// A, Bt: canonical bf16. bias: raw (flag dtype). 128x128 tile, BK=32,
// 256 thr = 4 waves (2x2), each wave 4x4 of 16x16x32 MFMA.
// ACT: 0 none, 1 exact GELU. RES: 0 none, 1 bf16 ws ptr, 2 raw (flag).
// STORE: 0 bf16, 1 flag-selected (fp32 when inputs fp32).
// ---------------------------------------------------------------------------
template <int ACT, int RES, int STORE>
__global__ __launch_bounds__(256) void gemm_bt(
    const u16* __restrict__ A, const u16* __restrict__ Bt,
    const void* __restrict__ bias, const void* __restrict__ res,
    void* __restrict__ C, int M, int N, int K, int moff,
    const int* __restrict__ flagp) {
    const int f = *flagp;
    __shared__ __align__(16) u16 As[128 * 32];
    __shared__ __align__(16) u16 Bs[128 * 32];
    const int tid = threadIdx.x;
    const int m0 = blockIdx.x * 128, n0 = blockIdx.y * 128;
    const int wave = tid >> 6, lane = tid & 63;
    const int wm = (wave & 1) * 64, wn = (wave >> 1) * 64;
    const int lm = lane & 15, quad = lane >> 4;
    const int srow = tid >> 1, skoff = (tid & 1) * 16;  // 32B of one row/thread

    f32x4 acc[4][4] = {};
    const u16* Ap = A + (size_t)(m0 + srow) * K + skoff;
    const u16* Bp = Bt + (size_t)(n0 + srow) * K + skoff;
    const int smo = srow * 32 + skoff;

    for (int k0 = 0; k0 < K; k0 += 32) {
        uint4 av0 = *(const uint4*)(Ap);
        uint4 av1 = *(const uint4*)(Ap + 8);
        uint4 bv0 = *(const uint4*)(Bp);
        uint4 bv1 = *(const uint4*)(Bp + 8);
        Ap += 32; Bp += 32;
        __syncthreads();                       // prior iter's ds_reads done
        *(uint4*)&As[smo] = av0;
        *(uint4*)&As[smo + 8] = av1;
        *(uint4*)&Bs[smo] = bv0;
        *(uint4*)&Bs[smo + 8] = bv1;
        __syncthreads();
        bf16x8 af[4], bfv[4];
#pragma unroll
        for (int i = 0; i < 4; i++)
            af[i] = *(const bf16x8*)&As[(wm + i * 16 + lm) * 32 + quad * 8];
#pragma unroll
        for (int j = 0; j < 4; j++)
            bfv[j] = *(const bf16x8*)&Bs[(wn + j * 16 + lm) * 32 + quad * 8];
#pragma unroll
        for (int i = 0; i < 4; i++)
#pragma unroll
            for (int j = 0; j < 4; j++)
                acc[i][j] = __builtin_amdgcn_mfma_f32_16x16x32_bf16(
                    af[i], bfv[j], acc[i][j], 0, 0, 0);
    }

    float bias_f[4];
#pragma unroll
    for (int j = 0; j < 4; j++)
        bias_f[j] = loadDyn(bias, n0 + wn + j * 16 + lm, f);
#pragma unroll
    for (int i = 0; i < 4; i++) {
#pragma unroll
        for (int r = 0; r < 4; r++) {
            int row = m0 + wm + i * 16 + quad * 4 + r;   // C/D: row=quad*4+reg
            size_t rb = (size_t)(moff + row) * N;
#pragma unroll
            for (int j = 0; j < 4; j++) {
                int col = n0 + wn + j * 16 + lm;          // C/D: col=lane&15
                float vv = acc[i][j][r] + bias_f[j];
                if (ACT == 1) vv = gelu_exact(vv);
                if (RES == 1) vv += b2f(((const u16*)res)[rb + col]);
                if (RES == 2) vv += loadDyn(res, rb + col, f);
                if (STORE == 0) ((u16*)C)[rb + col] = f2b(vv);
                else {
                    if (f) ((float*)C)[rb + col] = vv;
                    else   ((u16*)C)[rb + col] = f2b(vv);
                }
            }
        }
    }
}

// ---------------------------------------------------------------------------
// Masked attention, online softmax. Block = (h, qgroup of 64, b), 256 thr.
// Thread t owns query qrow=t>>2; score phase covers keys (t&3)*16..+16,
// PV phase covers dims (t&3)*16..+16. o may alias q: each element of q is
// read only by the block that writes it, q is staged to LDS first, and the
// write is the block's final act.
// ---------------------------------------------------------------------------
__global__ __launch_bounds__(256) void attn_k(
    const u16* q, const u16* __restrict__ k,
    const u16* __restrict__ v, const int* __restrict__ adj,
    u16* o) {
    const int h = blockIdx.x, qg = blockIdx.y, b = blockIdx.z;
    const int q0 = qg * 64;
    const int tid = threadIdx.x;
    const int qrow = tid >> 2;
    const int quarter = tid & 3;

    __shared__ __align__(16) float qs[64 * 64];   // 16 KB fp32 queries
    __shared__ __align__(16) u16 ks[64 * 64];     // 8 KB key chunk
    __shared__ __align__(16) u16 vs[64 * 64];     // 8 KB value chunk
    __shared__ float ss[64 * 64];                  // 16 KB scores/probs
    __shared__ float msm[64], lsm[64], alph[64];

    // stage q (bf16 -> fp32)
    {
        const int d0 = quarter * 16;
        const u16* src = q + ((size_t)(b * Nn + q0 + qrow)) * Dn + h * HDn + d0;
        u16x8 a0 = *(const u16x8*)src;
        u16x8 a1 = *(const u16x8*)(src + 8);
#pragma unroll
        for (int i = 0; i < 8; i++) qs[qrow * 64 + d0 + i] = b2f(a0[i]);
#pragma unroll
        for (int i = 0; i < 8; i++) qs[qrow * 64 + d0 + 8 + i] = b2f(a1[i]);
    }
    if (tid < 64) { msm[tid] = -3e38f; lsm[tid] = 0.f; }

    float Oacc[16];
#pragma unroll
    for (int i = 0; i < 16; i++) Oacc[i] = 0.f;

    for (int kb = 0; kb < Nn / 64; kb++) {
        const int kb0 = kb * 64;
        if (kb) __syncthreads();   // protect LDS reuse across iterations
        // stage K,V chunk
        {
            const int r = qrow, d0 = quarter * 16;
            const size_t gbase = ((size_t)(b * Nn + kb0 + r)) * Dn + h * HDn + d0;
            *(u16x8*)&ks[r * 64 + d0]     = *(const u16x8*)(k + gbase);
            *(u16x8*)&ks[r * 64 + d0 + 8] = *(const u16x8*)(k + gbase + 8);
            *(u16x8*)&vs[r * 64 + d0]     = *(const u16x8*)(v + gbase);
            *(u16x8*)&vs[r * 64 + d0 + 8] = *(const u16x8*)(v + gbase + 8);
        }
        __syncthreads();
        // scores for (qrow, 16 keys)
        {
            const float* qrp = &qs[qrow * 64];
            const size_t arow = ((size_t)b * Nn + (q0 + qrow)) * Nn + kb0;
#pragma unroll 4
            for (int kk = quarter * 16; kk < quarter * 16 + 16; kk++) {
                int a = adj[arow + kk];
                float sres;
                if (a == 0) {
                    sres = -3e38f;
                } else {
                    float dot = 0.f;
                    const u16x8* kp = (const u16x8*)&ks[kk * 64];
#pragma unroll
                    for (int c = 0; c < 8; c++) {
                        u16x8 kv = kp[c];
                        const float* qp = qrp + c * 8;
#pragma unroll
                        for (int e = 0; e < 8; e++) dot += qp[e] * b2f(kv[e]);
                    }
                    sres = dot * 0.125f;  // HD^-0.5
                }
                ss[qrow * 64 + kk] = sres;
            }
        }
        __syncthreads();
        // online softmax update (one thread per query)
        if (tid < 64) {
            float* srow = &ss[tid * 64];
            float mold = msm[tid];
            float cmax = -3e38f;
#pragma unroll 8
            for (int kk = 0; kk < 64; kk++) cmax = fmaxf(cmax, srow[kk]);
            float newm = fmaxf(mold, cmax);
            float a, sum = 0.f;
            if (newm <= -1e29f) {       // everything masked so far
                a = 1.0f;
#pragma unroll 8
                for (int kk = 0; kk < 64; kk++) srow[kk] = 0.f;
            } else {
                a = (mold <= -1e29f) ? 0.f : __expf(mold - newm);
#pragma unroll 8
                for (int kk = 0; kk < 64; kk++) {
                    float sc = srow[kk];
                    float p = (sc <= -1e29f) ? 0.f : __expf(sc - newm);
                    srow[kk] = p;
                    sum += p;
                }
            }
            lsm[tid] = lsm[tid] * a + sum;
            msm[tid] = newm;
            alph[tid] = a;
        }
        __syncthreads();
        // PV accumulate
        {
            const int d0 = quarter * 16;
            float a = alph[qrow];
#pragma unroll
            for (int d = 0; d < 16; d++) Oacc[d] *= a;
            const float* prow = &ss[qrow * 64];
            for (int kk = 0; kk < 64; kk++) {
                float p = prow[kk];
                if (p != 0.f) {
                    const u16x8* vp = (const u16x8*)&vs[kk * 64 + d0];
                    u16x8 v0 = vp[0], v1 = vp[1];
#pragma unroll
                    for (int e = 0; e < 8; e++) Oacc[e] += p * b2f(v0[e]);
#pragma unroll
                    for (int e = 0; e < 8; e++) Oacc[8 + e] += p * b2f(v1[e]);
                }
            }
        }
    }
    // write out (l==0 -> zeros, matches nan_to_num)
    {
        float l = lsm[qrow];
        float inv = (l > 0.f) ? 1.0f / l : 0.f;
        const int d0 = quarter * 16;
        u16* dst = o + ((size_t)(b * Nn + q0 + qrow)) * Dn + h * HDn + d0;
        u16x8 o0, o1;
#pragma unroll
        for (int e = 0; e < 8; e++) o0[e] = f2b(Oacc[e] * inv);
#pragma unroll
        for (int e = 0; e < 8; e++) o1[e] = f2b(Oacc[8 + e] * inv);
        *(u16x8*)dst = o0;
        *(u16x8*)(dst + 8) = o1;
    }
}

// ---------------------------------------------------------------------------
extern "C" void kernel_launch(void* const* d_in, const int* in_sizes, int n_in,
                              void* d_out, int out_size, void* d_ws,
                              size_t ws_size, hipStream_t stream) {
    const void* x   = d_in[0];
    const int* adj  = (const int*)d_in[1];
    const void* wq  = d_in[2];
    const void* bq  = d_in[3];
    const void* wk  = d_in[4];
    const void* bk  = d_in[5];
    const void* wv  = d_in[6];
    const void* bv  = d_in[7];
    const void* wo  = d_in[8];
    const void* bo  = d_in[9];
    const void* g1  = d_in[10];
    const void* b1  = d_in[11];
    const void* g2  = d_in[12];
    const void* b2  = d_in[13];
    const void* w1  = d_in[14];
    const void* bf1 = d_in[15];
    const void* w2  = d_in[16];
    const void* bf2 = d_in[17];

    // ---- workspace layout (~114 MiB total) ----
    char* ws = (char*)d_ws;
    size_t off = 0;
    auto alloc = [&](size_t bytes) -> char* {
        char* p = ws + off;
        off += (bytes + 255) & ~(size_t)255;
        return p;
    };
    int* flag = (int*)alloc(4);
    u16* wqT  = (u16*)alloc((size_t)Dn * Dn * 2);
    u16* wkT  = (u16*)alloc((size_t)Dn * Dn * 2);
    u16* wvT  = (u16*)alloc((size_t)Dn * Dn * 2);
    u16* woT  = (u16*)alloc((size_t)Dn * Dn * 2);
    u16* w1T  = (u16*)alloc((size_t)Dn * DFn * 2);
    u16* w2T  = (u16*)alloc((size_t)Dn * DFn * 2);
    const size_t S = (size_t)Mn * Dn * 2;          // 25.2 MB
    u16* Rh = (u16*)alloc(S);   // LN1 out h; later LN2 out h2
    u16* Rq = (u16*)alloc(S);   // Q; attn writes output in-place here
    u16* Rk = (u16*)alloc(S);   // K; later FFN-hidden chunk (4096x3072 bf16)
    u16* Rv = (u16*)alloc(S);   // V; later attn-block output (outb)

    // 1. sniff input dtype
    sniff_k<<<1, 256, 0, stream>>>((const u16*)x, flag);

    // 2. canonicalize + transpose weights
    dim3 tb(32, 8);
    transpose_k<<<dim3(Dn / 32, Dn / 32), tb, 0, stream>>>(wq, wqT, Dn, Dn, flag);
    transpose_k<<<dim3(Dn / 32, Dn / 32), tb, 0, stream>>>(wk, wkT, Dn, Dn, flag);
    transpose_k<<<dim3(Dn / 32, Dn / 32), tb, 0, stream>>>(wv, wvT, Dn, Dn, flag);
    transpose_k<<<dim3(Dn / 32, Dn / 32), tb, 0, stream>>>(wo, woT, Dn, Dn, flag);
    transpose_k<<<dim3(DFn / 32, Dn / 32), tb, 0, stream>>>(w1, w1T, Dn, DFn, flag);
    transpose_k<<<dim3(Dn / 32, DFn / 32), tb, 0, stream>>>(w2, w2T, DFn, Dn, flag);

    // 3. LN1: x(raw) -> Rh
    ln_k<1><<<Mn, 256, 0, stream>>>(x, g1, b1, Rh, flag);

    // 4. QKV projections
    gemm_bt<0, 0, 0><<<dim3(Mn / 128, Dn / 128), 256, 0, stream>>>(
        Rh, wqT, bq, nullptr, Rq, Mn, Dn, Dn, 0, flag);
    gemm_bt<0, 0, 0><<<dim3(Mn / 128, Dn / 128), 256, 0, stream>>>(
        Rh, wkT, bk, nullptr, Rk, Mn, Dn, Dn, 0, flag);
    gemm_bt<0, 0, 0><<<dim3(Mn / 128, Dn / 128), 256, 0, stream>>>(
        Rh, wvT, bv, nullptr, Rv, Mn, Dn, Dn, 0, flag);

    // 5. attention: Rq,Rk,Rv -> Rq (in-place over Q)
    attn_k<<<dim3(Hn, Nn / 64, Bn), 256, 0, stream>>>(Rq, Rk, Rv, adj, Rq);

    // 6. outb = attn @ wo + bo + x(raw residual) -> Rv
    gemm_bt<0, 2, 0><<<dim3(Mn / 128, Dn / 128), 256, 0, stream>>>(
        Rq, woT, bo, x, Rv, Mn, Dn, Dn, 0, flag);

    // 7. LN2: Rv(bf16) -> Rh
    ln_k<0><<<Mn, 256, 0, stream>>>(Rv, g2, b2, Rh, flag);

    // 8. FFN in 4 M-chunks; hidden chunk lives in Rk (exactly fits)
    for (int c = 0; c < Mn / MCHUNK; c++) {
        gemm_bt<1, 0, 0><<<dim3(MCHUNK / 128, DFn / 128), 256, 0, stream>>>(
            Rh + (size_t)c * MCHUNK * Dn, w1T, bf1, nullptr, Rk,
            MCHUNK, DFn, Dn, 0, flag);
        gemm_bt<0, 1, 1><<<dim3(MCHUNK / 128, Dn / 128), 256, 0, stream>>>(
            Rk, w2T, bf2, Rv, d_out, MCHUNK, Dn, DFn, c * MCHUNK, flag);
    }
}

// Round 4
// 1034.175 us; speedup vs baseline: 2.4159x; 2.4159x over previous
//
#include <hip/hip_runtime.h>

// ---------------------------------------------------------------------------
// DenseGATLayer: LN1 -> QKV proj -> adj-masked MHA -> WO proj + residual
//                -> LN2 -> GELU FFN -> residual
// B=32 N=512 D=768 H=12 HD=64. Compute: bf16 MFMA, fp32 accumulation.
// R4: (1) MFMA flash-attention (was VALU, 1645us, 6.5e8 LDS conflicts);
//     (2) GEMM staging via global_load_lds width=16 (m97 ladder step).
// ---------------------------------------------------------------------------

#define Bn 32
#define Nn 512
#define Dn 768
#define Hn 12
#define HDn 64
#define Mn (Bn * Nn)      // 16384 rows
#define DFn 3072          // FFN hidden
#define MCHUNK 4096       // FFN M-chunk rows

typedef unsigned short u16;
typedef short bf16x8 __attribute__((ext_vector_type(8)));      // 8 bf16 (4 VGPR)
typedef float f32x4 __attribute__((ext_vector_type(4)));       // MFMA acc
typedef unsigned short u16x8 __attribute__((ext_vector_type(8)));

__device__ __forceinline__ float b2f(u16 u) {
    return __uint_as_float(((unsigned int)u) << 16);
}
__device__ __forceinline__ u16 f2b(float f) {
    unsigned int u = __float_as_uint(f);
    u += 0x7fffu + ((u >> 16) & 1u);   // RNE
    return (u16)(u >> 16);
}
__device__ __forceinline__ float loadDyn(const void* p, size_t i, int f) {
    return f ? ((const float*)p)[i] : b2f(((const u16*)p)[i]);
}
__device__ __forceinline__ float gelu_exact(float x) {
    return 0.5f * x * (1.0f + erff(x * 0.70710678118654752f));
}
__device__ __forceinline__ float waveRedSum(float v) {
#pragma unroll
    for (int off = 32; off > 0; off >>= 1) v += __shfl_xor(v, off, 64);
    return v;
}

// async global->LDS, 16B per lane. LDS dest must be wave-uniform base +
// lane*16 (HW constraint, m104/m108). Pointer casts via integer round-trip:
// as3 pointers are the low 32 bits of the flat LDS address (4GB-aligned
// aperture), as1 == flat for global.
__device__ __forceinline__ void gl_lds16(const u16* g, u16* l) {
    __builtin_amdgcn_global_load_lds(
        (const __attribute__((address_space(1))) void*)(unsigned long long)(const void*)g,
        (__attribute__((address_space(3))) void*)(unsigned)(unsigned long long)(void*)l,
        16, 0, 0);
}

// ---------------------------------------------------------------------------
// Dtype sniffer (bf16 vs fp32 inputs) — see R2 notes. flag=1 => fp32.
// ---------------------------------------------------------------------------
__global__ __launch_bounds__(256) void sniff_k(const u16* __restrict__ x,
                                               int* __restrict__ flag) {
    __shared__ int tot;
    if (threadIdx.x == 0) tot = 0;
    __syncthreads();
    int cnt = 0;
    for (int i = threadIdx.x; i < 131072; i += 256) {
        u16 u = x[i];
        cnt += ((u & 0x7F80) == 0x7F80) ? 1 : 0;
    }
    atomicAdd(&tot, cnt);
    __syncthreads();
    if (threadIdx.x == 0) *flag = (tot > 32) ? 1 : 0;
}

// ---------------------------------------------------------------------------
// Transpose raw weight -> canonical bf16: out[c][r] = in[r][c]
// ---------------------------------------------------------------------------
__global__ __launch_bounds__(256) void transpose_k(
    const void* __restrict__ in, u16* __restrict__ out, int R, int C,
    const int* __restrict__ flagp) {
    const int f = *flagp;
    __shared__ u16 tile[32][33];
    int c0 = blockIdx.x * 32, r0 = blockIdx.y * 32;
    int tx = threadIdx.x, ty = threadIdx.y;  // 32 x 8
#pragma unroll
    for (int i = 0; i < 32; i += 8)
        tile[ty + i][tx] = f2b(loadDyn(in, (size_t)(r0 + ty + i) * C + c0 + tx, f));
    __syncthreads();
#pragma unroll
    for (int i = 0; i < 32; i += 8)
        out[(size_t)(c0 + ty + i) * R + r0 + tx] = tile[tx][ty + i];
}

// ---------------------------------------------------------------------------
// LayerNorm over D=768, one block (256 thr) per row.
// ---------------------------------------------------------------------------
template <int XDYN>
__global__ __launch_bounds__(256) void ln_k(
    const void* __restrict__ x, const void* __restrict__ g,
    const void* __restrict__ b, u16* __restrict__ y,
    const int* __restrict__ flagp) {
    const int f = *flagp;
    const int row = blockIdx.x;
    const int tid = threadIdx.x;
    const size_t base = (size_t)row * Dn;
    float v[3];
#pragma unroll
    for (int i = 0; i < 3; i++) {
        size_t idx = base + tid + i * 256;
        v[i] = XDYN ? loadDyn(x, idx, f) : b2f(((const u16*)x)[idx]);
    }
    __shared__ float red[8];
    float s = waveRedSum(v[0] + v[1] + v[2]);
    if ((tid & 63) == 0) red[tid >> 6] = s;
    __syncthreads();
    float mu = (red[0] + red[1] + red[2] + red[3]) * (1.0f / Dn);
    float d2 = 0.f;
#pragma unroll
    for (int i = 0; i < 3; i++) { float d = v[i] - mu; d2 += d * d; }
    d2 = waveRedSum(d2);
    if ((tid & 63) == 0) red[4 + (tid >> 6)] = d2;
    __syncthreads();
    float var = (red[4] + red[5] + red[6] + red[7]) * (1.0f / Dn);
    float rstd = rsqrtf(var + 1e-5f);
#pragma unroll
    for (int i = 0; i < 3; i++) {
        int c = tid + i * 256;
        float o = (v[i] - mu) * rstd * loadDyn(g, c, f) + loadDyn(b, c, f);
        y[base + c] = f2b(o);
    }
}

// ---------------------------------------------------------------------------
// GEMM: C[moff+M rows][N] = epi( A[M][K] @ Bt[N][K]^T + bias[N] (+res) )
// 128x128 tile, BK=32, 4 waves (2x2), wave = 4x4 of 16x16x32 MFMA.
// Staging: global_load_lds width=16; LDS [128 rows][32 u16] row-major,
// lane idx writes bytes idx*16 (row=idx>>2, kchunk=(idx&3)*8) -> each
// wave's dest = uniform base + lane*16. ACT 1=GELU; RES 1=bf16 ptr, 2=raw;
// STORE 1=flag-selected output dtype.
// ---------------------------------------------------------------------------
template <int ACT, int RES, int STORE>
__global__ __launch_bounds__(256) void gemm_bt(
    const u16* __restrict__ A, const u16* __restrict__ Bt,
    const void* __restrict__ bias, const void* __restrict__ res,
    void* __restrict__ C, int M, int N, int K, int moff,
    const int* __restrict__ flagp) {
    const int f = *flagp;
    __shared__ __align__(16) u16 As[128 * 32];
    __shared__ __align__(16) u16 Bs[128 * 32];
    const int tid = threadIdx.x;
    const int m0 = blockIdx.x * 128, n0 = blockIdx.y * 128;
    const int wave = tid >> 6, lane = tid & 63;
    const int wm = (wave & 1) * 64, wn = (wave >> 1) * 64;
    const int lm = lane & 15, quad = lane >> 4;

    const int i0 = tid, i1 = tid + 256;
    const u16* Ap0 = A + (size_t)(m0 + (i0 >> 2)) * K + (i0 & 3) * 8;
    const u16* Ap1 = A + (size_t)(m0 + (i1 >> 2)) * K + (i1 & 3) * 8;
    const u16* Bp0 = Bt + (size_t)(n0 + (i0 >> 2)) * K + (i0 & 3) * 8;
    const u16* Bp1 = Bt + (size_t)(n0 + (i1 >> 2)) * K + (i1 & 3) * 8;
    u16* Ad0 = &As[i0 * 8]; u16* Ad1 = &As[i1 * 8];
    u16* Bd0 = &Bs[i0 * 8]; u16* Bd1 = &Bs[i1 * 8];

    f32x4 acc[4][4] = {};
    for (int k0 = 0; k0 < K; k0 += 32) {
        __syncthreads();                       // prior iter's ds_reads done
        gl_lds16(Ap0, Ad0); gl_lds16(Ap1, Ad1);
        gl_lds16(Bp0, Bd0); gl_lds16(Bp1, Bd1);
        Ap0 += 32; Ap1 += 32; Bp0 += 32; Bp1 += 32;
        __syncthreads();                       // drains vmcnt (sync semantics)
        bf16x8 af[4], bfv[4];
#pragma unroll
        for (int i = 0; i < 4; i++)
            af[i] = *(const bf16x8*)&As[(wm + i * 16 + lm) * 32 + quad * 8];
#pragma unroll
        for (int j = 0; j < 4; j++)
            bfv[j] = *(const bf16x8*)&Bs[(wn + j * 16 + lm) * 32 + quad * 8];
#pragma unroll
        for (int i = 0; i < 4; i++)
#pragma unroll
            for (int j = 0; j < 4; j++)
                acc[i][j] = __builtin_amdgcn_mfma_f32_16x16x32_bf16(
                    af[i], bfv[j], acc[i][j], 0, 0, 0);
    }

    float bias_f[4];
#pragma unroll
    for (int j = 0; j < 4; j++)
        bias_f[j] = loadDyn(bias, n0 + wn + j * 16 + lm, f);
#pragma unroll
    for (int i = 0; i < 4; i++) {
#pragma unroll
        for (int r = 0; r < 4; r++) {
            int row = m0 + wm + i * 16 + quad * 4 + r;   // C/D: row=quad*4+reg
            size_t rb = (size_t)(moff + row) * N;
#pragma unroll
            for (int j = 0; j < 4; j++) {
                int col = n0 + wn + j * 16 + lm;          // C/D: col=lane&15
                float vv = acc[i][j][r] + bias_f[j];
                if (ACT == 1) vv = gelu_exact(vv);
                if (RES == 1) vv += b2f(((const u16*)res)[rb + col]);
                if (RES == 2) vv += loadDyn(res, rb + col, f);
                if (STORE == 0) ((u16*)C)[rb + col] = f2b(vv);
                else {
                    if (f) ((float*)C)[rb + col] = vv;
                    else   ((u16*)C)[rb + col] = f2b(vv);
                }
            }
        }
    }
}

// ---------------------------------------------------------------------------
// MFMA masked flash-attention. Block = (h, q-tile of 64, b), 256 thr = 4
// waves; wave w owns query rows wm=w*16..+16. Per 64-key chunk:
//   S = Q K^T (MFMA, C-layout: row=quad*4+r, col=j*16+lm)
//   mask(adj) + online softmax in registers (row state per (quad,r),
//   reductions via shfl_xor over the 16 lm lanes)
//   P -> LDS (bf16) -> A-layout fragments; O += P V via MFMA with V staged
//   transposed (Vt[dim][key]) so B-fragments are contiguous ds_read_b128.
// LDS pitch 72 u16 (=144B) keeps 16B alignment, 2-way banks (free).
// o may alias q: block writes exactly the (rows, dim-slice) only it reads.
// ---------------------------------------------------------------------------
__global__ __launch_bounds__(256) void attn_mfma_k(
    const u16* q, const u16* __restrict__ k,
    const u16* __restrict__ v, const int* __restrict__ adj, u16* o) {
    const int h = blockIdx.x, qg = blockIdx.y, b = blockIdx.z;
    const int q0 = qg * 64;
    const int tid = threadIdx.x;
    const int wave = tid >> 6, lane = tid & 63;
    const int lm = lane & 15, quad = lane >> 4;
    const int wm = wave * 16;

    __shared__ __align__(16) u16 Qs[64 * 72];
    __shared__ __align__(16) u16 Ks[64 * 72];
    __shared__ __align__(16) u16 Vts[64 * 72];
    __shared__ __align__(16) u16 Ps[64 * 72];

    // stage Q tile: thread -> row=tid>>2, 16 dims at (tid&3)*16
    {
        const int row = tid >> 2, dc = (tid & 3) * 16;
        const u16* src = q + ((size_t)(b * Nn + q0 + row)) * Dn + h * HDn + dc;
        *(u16x8*)&Qs[row * 72 + dc]     = *(const u16x8*)src;
        *(u16x8*)&Qs[row * 72 + dc + 8] = *(const u16x8*)(src + 8);
    }

    float m_i[4], l_i[4];           // row = wm + quad*4 + r
#pragma unroll
    for (int r = 0; r < 4; r++) { m_i[r] = -3e38f; l_i[r] = 0.f; }
    f32x4 Oacc[4] = {};             // j = dim tile (dim = j*16+lm)

    for (int kb = 0; kb < Nn / 64; kb++) {
        const int kb0 = kb * 64;
        __syncthreads();   // prior iter's Ks/Vts/Ps reads done; Q staged (kb=0)
        // stage K row-major and V transposed
        {
            const int row = tid >> 2, dc = (tid & 3) * 16;
            const u16* ksrc = k + ((size_t)(b * Nn + kb0 + row)) * Dn + h * HDn + dc;
            u16x8 k0v = *(const u16x8*)ksrc;
            u16x8 k1v = *(const u16x8*)(ksrc + 8);
            *(u16x8*)&Ks[row * 72 + dc]     = k0v;
            *(u16x8*)&Ks[row * 72 + dc + 8] = k1v;
            const u16* vsrc = v + ((size_t)(b * Nn + kb0 + row)) * Dn + h * HDn + dc;
            u16x8 v0v = *(const u16x8*)vsrc;
            u16x8 v1v = *(const u16x8*)(vsrc + 8);
#pragma unroll
            for (int e = 0; e < 8; e++) Vts[(dc + e) * 72 + row] = v0v[e];
#pragma unroll
            for (int e = 0; e < 8; e++) Vts[(dc + 8 + e) * 72 + row] = v1v[e];
        }
        __syncthreads();
        // S = Q K^T for this wave's 16 rows x 64 keys
        f32x4 sacc[4] = {};
#pragma unroll
        for (int s = 0; s < 2; s++) {
            bf16x8 aq = *(const bf16x8*)&Qs[(wm + lm) * 72 + s * 32 + quad * 8];
#pragma unroll
            for (int j = 0; j < 4; j++) {
                bf16x8 bk = *(const bf16x8*)&Ks[(j * 16 + lm) * 72 + s * 32 + quad * 8];
                sacc[j] = __builtin_amdgcn_mfma_f32_16x16x32_bf16(aq, bk, sacc[j], 0, 0, 0);
            }
        }
        // mask + scale + row max (rows owned per (quad,r))
        float pmax[4];
#pragma unroll
        for (int r = 0; r < 4; r++) pmax[r] = -3e38f;
#pragma unroll
        for (int r = 0; r < 4; r++) {
            const size_t arow = ((size_t)b * Nn + (q0 + wm + quad * 4 + r)) * Nn + kb0;
#pragma unroll
            for (int j = 0; j < 4; j++) {
                int am = adj[arow + j * 16 + lm];
                float sc = (am != 0) ? sacc[j][r] * 0.125f : -3e38f;
                sacc[j][r] = sc;
                pmax[r] = fmaxf(pmax[r], sc);
            }
        }
#pragma unroll
        for (int r = 0; r < 4; r++) {
            float mv = pmax[r];
            mv = fmaxf(mv, __shfl_xor(mv, 1, 64));
            mv = fmaxf(mv, __shfl_xor(mv, 2, 64));
            mv = fmaxf(mv, __shfl_xor(mv, 4, 64));
            mv = fmaxf(mv, __shfl_xor(mv, 8, 64));
            pmax[r] = mv;
        }
        // online update; exp(-3e38 - -3e38)=exp(0)=1 is harmless (O=0,l=0)
        float alpha[4];
#pragma unroll
        for (int r = 0; r < 4; r++) {
            float newm = fmaxf(m_i[r], pmax[r]);
            alpha[r] = __expf(m_i[r] - newm);
            m_i[r] = newm;
            float s_ = 0.f;
#pragma unroll
            for (int j = 0; j < 4; j++) {
                float sc = sacc[j][r];
                float p = (sc > -1e30f) ? __expf(sc - newm) : 0.f;
                sacc[j][r] = p;
                s_ += p;
            }
            s_ += __shfl_xor(s_, 1, 64);
            s_ += __shfl_xor(s_, 2, 64);
            s_ += __shfl_xor(s_, 4, 64);
            s_ += __shfl_xor(s_, 8, 64);
            l_i[r] = l_i[r] * alpha[r] + s_;
        }
        // P (C-layout regs) -> LDS bf16 (A-layout source for PV)
#pragma unroll
        for (int r = 0; r < 4; r++)
#pragma unroll
            for (int j = 0; j < 4; j++)
                Ps[(wm + quad * 4 + r) * 72 + j * 16 + lm] = f2b(sacc[j][r]);
        // rescale O while P lands
#pragma unroll
        for (int j = 0; j < 4; j++)
#pragma unroll
            for (int r = 0; r < 4; r++) Oacc[j][r] *= alpha[r];
        __syncthreads();
        // O += P V
#pragma unroll
        for (int s = 0; s < 2; s++) {
            bf16x8 ap = *(const bf16x8*)&Ps[(wm + lm) * 72 + s * 32 + quad * 8];
#pragma unroll
            for (int j = 0; j < 4; j++) {
                bf16x8 bv = *(const bf16x8*)&Vts[(j * 16 + lm) * 72 + s * 32 + quad * 8];
                Oacc[j] = __builtin_amdgcn_mfma_f32_16x16x32_bf16(ap, bv, Oacc[j], 0, 0, 0);
            }
        }
    }
    // write out: O/l (l==0 -> 0, matches nan_to_num)
    float inv[4];
#pragma unroll
    for (int r = 0; r < 4; r++) inv[r] = (l_i[r] > 0.f) ? 1.0f / l_i[r] : 0.f;
#pragma unroll
    for (int r = 0; r < 4; r++) {
        const int row = q0 + wm + quad * 4 + r;
        u16* dst = o + ((size_t)(b * Nn + row)) * Dn + h * HDn;
#pragma unroll
        for (int j = 0; j < 4; j++)
            dst[j * 16 + lm] = f2b(Oacc[j][r] * inv[r]);
    }
}

// ---------------------------------------------------------------------------
extern "C" void kernel_launch(void* const* d_in, const int* in_sizes, int n_in,
                              void* d_out, int out_size, void* d_ws,
                              size_t ws_size, hipStream_t stream) {
    const void* x   = d_in[0];
    const int* adj  = (const int*)d_in[1];
    const void* wq  = d_in[2];
    const void* bq  = d_in[3];
    const void* wk  = d_in[4];
    const void* bk  = d_in[5];
    const void* wv  = d_in[6];
    const void* bv  = d_in[7];
    const void* wo  = d_in[8];
    const void* bo  = d_in[9];
    const void* g1  = d_in[10];
    const void* b1  = d_in[11];
    const void* g2  = d_in[12];
    const void* b2  = d_in[13];
    const void* w1  = d_in[14];
    const void* bf1 = d_in[15];
    const void* w2  = d_in[16];
    const void* bf2 = d_in[17];

    char* ws = (char*)d_ws;
    size_t off = 0;
    auto alloc = [&](size_t bytes) -> char* {
        char* p = ws + off;
        off += (bytes + 255) & ~(size_t)255;
        return p;
    };
    int* flag = (int*)alloc(4);
    u16* wqT  = (u16*)alloc((size_t)Dn * Dn * 2);
    u16* wkT  = (u16*)alloc((size_t)Dn * Dn * 2);
    u16* wvT  = (u16*)alloc((size_t)Dn * Dn * 2);
    u16* woT  = (u16*)alloc((size_t)Dn * Dn * 2);
    u16* w1T  = (u16*)alloc((size_t)Dn * DFn * 2);
    u16* w2T  = (u16*)alloc((size_t)Dn * DFn * 2);
    const size_t S = (size_t)Mn * Dn * 2;          // 25.2 MB
    u16* Rh = (u16*)alloc(S);   // LN1 out h; later LN2 out h2
    u16* Rq = (u16*)alloc(S);   // Q; attn writes output in-place here
    u16* Rk = (u16*)alloc(S);   // K; later FFN-hidden chunk
    u16* Rv = (u16*)alloc(S);   // V; later attn-block output (outb)

    sniff_k<<<1, 256, 0, stream>>>((const u16*)x, flag);

    dim3 tb(32, 8);
    transpose_k<<<dim3(Dn / 32, Dn / 32), tb, 0, stream>>>(wq, wqT, Dn, Dn, flag);
    transpose_k<<<dim3(Dn / 32, Dn / 32), tb, 0, stream>>>(wk, wkT, Dn, Dn, flag);
    transpose_k<<<dim3(Dn / 32, Dn / 32), tb, 0, stream>>>(wv, wvT, Dn, Dn, flag);
    transpose_k<<<dim3(Dn / 32, Dn / 32), tb, 0, stream>>>(wo, woT, Dn, Dn, flag);
    transpose_k<<<dim3(DFn / 32, Dn / 32), tb, 0, stream>>>(w1, w1T, Dn, DFn, flag);
    transpose_k<<<dim3(Dn / 32, DFn / 32), tb, 0, stream>>>(w2, w2T, DFn, Dn, flag);

    // LN1: x(raw) -> Rh
    ln_k<1><<<Mn, 256, 0, stream>>>(x, g1, b1, Rh, flag);

    // QKV projections
    gemm_bt<0, 0, 0><<<dim3(Mn / 128, Dn / 128), 256, 0, stream>>>(
        Rh, wqT, bq, nullptr, Rq, Mn, Dn, Dn, 0, flag);
    gemm_bt<0, 0, 0><<<dim3(Mn / 128, Dn / 128), 256, 0, stream>>>(
        Rh, wkT, bk, nullptr, Rk, Mn, Dn, Dn, 0, flag);
    gemm_bt<0, 0, 0><<<dim3(Mn / 128, Dn / 128), 256, 0, stream>>>(
        Rh, wvT, bv, nullptr, Rv, Mn, Dn, Dn, 0, flag);

    // attention: Rq,Rk,Rv -> Rq (in-place over Q)
    attn_mfma_k<<<dim3(Hn, Nn / 64, Bn), 256, 0, stream>>>(Rq, Rk, Rv, adj, Rq);

    // outb = attn @ wo + bo + x(raw residual) -> Rv
    gemm_bt<0, 2, 0><<<dim3(Mn / 128, Dn / 128), 256, 0, stream>>>(
        Rq, woT, bo, x, Rv, Mn, Dn, Dn, 0, flag);

    // LN2: Rv -> Rh
    ln_k<0><<<Mn, 256, 0, stream>>>(Rv, g2, b2, Rh, flag);

    // FFN in 4 M-chunks; hidden chunk lives in Rk
    for (int c = 0; c < Mn / MCHUNK; c++) {
        gemm_bt<1, 0, 0><<<dim3(MCHUNK / 128, DFn / 128), 256, 0, stream>>>(
            Rh + (size_t)c * MCHUNK * Dn, w1T, bf1, nullptr, Rk,
            MCHUNK, DFn, Dn, 0, flag);
        gemm_bt<0, 1, 1><<<dim3(MCHUNK / 128, Dn / 128), 256, 0, stream>>>(
            Rk, w2T, bf2, Rv, d_out, MCHUNK, Dn, DFn, c * MCHUNK, flag);
    }
}

// Round 5
// 906.797 us; speedup vs baseline: 2.7552x; 1.1405x over previous
//
#include <hip/hip_runtime.h>

// ---------------------------------------------------------------------------
// DenseGATLayer: LN1 -> QKV proj -> adj-masked MHA -> WO proj + residual
//                -> LN2 -> GELU FFN -> residual
// B=32 N=512 D=768 H=12 HD=64. bf16 MFMA, fp32 accumulation. Inputs proven
// bf16 at runtime (R4 passed via bf16 readback); dyn-dtype paths kept as
// insurance. R5: adj bitmask + global V-pretranspose (attn was LDS-write/
// fetch bound); GEMM wave-tile 64x128 (LDS-read-BW theory); vector LN.
// ---------------------------------------------------------------------------

#define Bn 32
#define Nn 512
#define Dn 768
#define Hn 12
#define HDn 64
#define Mn (Bn * Nn)      // 16384 rows
#define DFn 3072          // FFN hidden
#define MCHUNK 8192       // FFN M-chunk rows (hidden = 50.3 MB -> Rq+Rk)

typedef unsigned short u16;
typedef unsigned long long u64;
typedef short bf16x8 __attribute__((ext_vector_type(8)));
typedef float f32x4 __attribute__((ext_vector_type(4)));
typedef unsigned short u16x8 __attribute__((ext_vector_type(8)));

__device__ __forceinline__ float b2f(u16 u) {
    return __uint_as_float(((unsigned int)u) << 16);
}
__device__ __forceinline__ u16 f2b(float f) {
    unsigned int u = __float_as_uint(f);
    u += 0x7fffu + ((u >> 16) & 1u);   // RNE
    return (u16)(u >> 16);
}
__device__ __forceinline__ float loadDyn(const void* p, size_t i, int f) {
    return f ? ((const float*)p)[i] : b2f(((const u16*)p)[i]);
}
__device__ __forceinline__ float gelu_exact(float x) {
    return 0.5f * x * (1.0f + erff(x * 0.70710678118654752f));
}

// async global->LDS, 16B/lane; LDS dest = wave-uniform base + lane*16.
__device__ __forceinline__ void gl_lds16(const u16* g, u16* l) {
    __builtin_amdgcn_global_load_lds(
        (const __attribute__((address_space(1))) void*)(unsigned long long)(const void*)g,
        (__attribute__((address_space(3))) void*)(unsigned)(unsigned long long)(void*)l,
        16, 0, 0);
}

// ---------------------------------------------------------------------------
// Dtype sniffer (bf16 vs fp32 inputs). flag=1 => fp32. (R4 ran flag=0.)
// ---------------------------------------------------------------------------
__global__ __launch_bounds__(256) void sniff_k(const u16* __restrict__ x,
                                               int* __restrict__ flag) {
    __shared__ int tot;
    if (threadIdx.x == 0) tot = 0;
    __syncthreads();
    int cnt = 0;
    for (int i = threadIdx.x; i < 131072; i += 256) {
        u16 u = x[i];
        cnt += ((u & 0x7F80) == 0x7F80) ? 1 : 0;
    }
    atomicAdd(&tot, cnt);
    __syncthreads();
    if (threadIdx.x == 0) *flag = (tot > 32) ? 1 : 0;
}

// ---------------------------------------------------------------------------
// adj -> bitmask: mask[row*8 + seg] bit j = (adj[row][seg*64+j] != 0).
// 1 MB total; removes the 12x-redundant adj reads in attention.
// ---------------------------------------------------------------------------
__global__ __launch_bounds__(256) void mask_build_k(
    const int* __restrict__ adj, u64* __restrict__ mask) {
    const int idx = blockIdx.x * 256 + threadIdx.x;   // Mn*8 = 131072 ids
    const size_t base = (size_t)(idx >> 3) * Nn + (size_t)(idx & 7) * 64;
    const int4* p = (const int4*)(adj + base);
    u64 m = 0;
#pragma unroll
    for (int c = 0; c < 16; c++) {
        int4 a = p[c];
        if (a.x) m |= 1ull << (c * 4 + 0);
        if (a.y) m |= 1ull << (c * 4 + 1);
        if (a.z) m |= 1ull << (c * 4 + 2);
        if (a.w) m |= 1ull << (c * 4 + 3);
    }
    mask[idx] = m;
}

// ---------------------------------------------------------------------------
// Transpose raw weight -> canonical bf16: out[c][r] = in[r][c]
// ---------------------------------------------------------------------------
__global__ __launch_bounds__(256) void transpose_k(
    const void* __restrict__ in, u16* __restrict__ out, int R, int C,
    const int* __restrict__ flagp) {
    const int f = *flagp;
    __shared__ u16 tile[32][33];
    int c0 = blockIdx.x * 32, r0 = blockIdx.y * 32;
    int tx = threadIdx.x, ty = threadIdx.y;  // 32 x 8
#pragma unroll
    for (int i = 0; i < 32; i += 8)
        tile[ty + i][tx] = f2b(loadDyn(in, (size_t)(r0 + ty + i) * C + c0 + tx, f));
    __syncthreads();
#pragma unroll
    for (int i = 0; i < 32; i += 8)
        out[(size_t)(c0 + ty + i) * R + r0 + tx] = tile[tx][ty + i];
}

// ---------------------------------------------------------------------------
// V [b][n][h][d] -> Vt [b*H+h][d][n]  (so attention stages V^T vectorized)
// ---------------------------------------------------------------------------
__global__ __launch_bounds__(256) void vtrans_k(
    const u16* __restrict__ v, u16* __restrict__ vt) {
    __shared__ u16 tile[32][33];
    const int bh = blockIdx.z;                 // b*Hn + h
    const int d0 = blockIdx.x * 32;            // 0 / 32
    const int n0 = blockIdx.y * 32;
    const int b = bh / Hn, h = bh % Hn;
    const int tx = threadIdx.x, ty = threadIdx.y;   // 32 x 8
#pragma unroll
    for (int i = 0; i < 32; i += 8)
        tile[ty + i][tx] =
            v[(size_t)(b * Nn + n0 + ty + i) * Dn + h * HDn + d0 + tx];
    __syncthreads();
#pragma unroll
    for (int i = 0; i < 32; i += 8)
        vt[((size_t)bh * HDn + d0 + ty + i) * Nn + n0 + tx] = tile[tx][ty + i];
}

// ---------------------------------------------------------------------------
// LayerNorm over D=768. 8 rows/block, 32 lanes/row, u16x8 vector loads.
// ---------------------------------------------------------------------------
template <int XDYN>
__global__ __launch_bounds__(256) void ln_k(
    const void* __restrict__ x, const void* __restrict__ g,
    const void* __restrict__ b, u16* __restrict__ y,
    const int* __restrict__ flagp) {
    const int f = *flagp;
    const int t = threadIdx.x;
    const int row = blockIdx.x * 8 + (t >> 5);
    const int l32 = t & 31;
    const size_t base = (size_t)row * Dn;
    float v[24];
    if (XDYN == 0 || f == 0) {   // bf16 path (ws buffers always bf16)
        const u16* xp = (const u16*)x;
#pragma unroll
        for (int kk = 0; kk < 3; kk++) {
            u16x8 a = *(const u16x8*)&xp[base + kk * 256 + l32 * 8];
#pragma unroll
            for (int e = 0; e < 8; e++) v[kk * 8 + e] = b2f(a[e]);
        }
    } else {
#pragma unroll
        for (int kk = 0; kk < 3; kk++)
#pragma unroll
            for (int e = 0; e < 8; e++)
                v[kk * 8 + e] = loadDyn(x, base + kk * 256 + l32 * 8 + e, f);
    }
    float s = 0.f;
#pragma unroll
    for (int i = 0; i < 24; i++) s += v[i];
#pragma unroll
    for (int off = 1; off <= 16; off <<= 1) s += __shfl_xor(s, off, 64);
    const float mu = s * (1.0f / Dn);
    float d2 = 0.f;
#pragma unroll
    for (int i = 0; i < 24; i++) { float d = v[i] - mu; d2 += d * d; }
#pragma unroll
    for (int off = 1; off <= 16; off <<= 1) d2 += __shfl_xor(d2, off, 64);
    const float rstd = rsqrtf(d2 * (1.0f / Dn) + 1e-5f);
#pragma unroll
    for (int kk = 0; kk < 3; kk++) {
        const int c0 = kk * 256 + l32 * 8;
        u16x8 o;
        if (f == 0) {
            u16x8 gv = *(const u16x8*)&((const u16*)g)[c0];
            u16x8 bv = *(const u16x8*)&((const u16*)b)[c0];
#pragma unroll
            for (int e = 0; e < 8; e++)
                o[e] = f2b((v[kk * 8 + e] - mu) * rstd * b2f(gv[e]) + b2f(bv[e]));
        } else {
#pragma unroll
            for (int e = 0; e < 8; e++)
                o[e] = f2b((v[kk * 8 + e] - mu) * rstd * loadDyn(g, c0 + e, f)
                           + loadDyn(b, c0 + e, f));
        }
        *(u16x8*)&y[base + c0] = o;
    }
}

// ---------------------------------------------------------------------------
// GEMM: C[moff+M][N] = epi( A[M][K] @ Bt[N][K]^T + bias (+res) ).
// Block tile 128 x (2*WN), BK=32, 4 waves (2x2); wave tile 64 x WN.
// WN=128 raises FLOP per LDS-read-byte 32 -> 43.7 (LDS-BW-bound theory).
// Staging via global_load_lds w16, linear chunk map (wave-uniform+lane*16).
// ---------------------------------------------------------------------------
template <int ACT, int RES, int STORE, int WN>
__global__ __launch_bounds__(256, 2) void gemm_bt(
    const u16* __restrict__ A, const u16* __restrict__ Bt,
    const void* __restrict__ bias, const void* __restrict__ res,
    void* __restrict__ C, int M, int N, int K, int moff,
    const int* __restrict__ flagp) {
    constexpr int BN = 2 * WN;
    constexpr int NJ = WN / 16;       // B-fragments per wave
    constexpr int NB = BN / 64;       // B staging chunks per thread
    const int f = *flagp;
    __shared__ __align__(16) u16 As[128 * 32];
    __shared__ __align__(16) u16 Bs[BN * 32];
    const int tid = threadIdx.x;
    const int m0 = blockIdx.x * 128, n0 = blockIdx.y * BN;
    const int wave = tid >> 6, lane = tid & 63;
    const int wm = (wave & 1) * 64, wn = (wave >> 1) * WN;
    const int lm = lane & 15, quad = lane >> 4;

    const int koff = (tid & 3) * 8;
    const int srow = tid >> 2;                       // 0..63
    const u16* gA[2]; u16* lA[2];
    const u16* gB[NB]; u16* lB[NB];
#pragma unroll
    for (int i = 0; i < 2; i++) {
        gA[i] = A + (size_t)(m0 + srow + i * 64) * K + koff;
        lA[i] = &As[(tid + i * 256) * 8];
    }
#pragma unroll
    for (int i = 0; i < NB; i++) {
        gB[i] = Bt + (size_t)(n0 + srow + i * 64) * K + koff;
        lB[i] = &Bs[(tid + i * 256) * 8];
    }

    f32x4 acc[4][NJ] = {};
    for (int k0 = 0; k0 < K; k0 += 32) {
        __syncthreads();                  // prior iter's ds_reads done
#pragma unroll
        for (int i = 0; i < 2; i++) { gl_lds16(gA[i], lA[i]); gA[i] += 32; }
#pragma unroll
        for (int i = 0; i < NB; i++) { gl_lds16(gB[i], lB[i]); gB[i] += 32; }
        __syncthreads();                  // drains vmcnt (barrier semantics)
        bf16x8 af[4], bfv[NJ];
#pragma unroll
        for (int i = 0; i < 4; i++)
            af[i] = *(const bf16x8*)&As[(wm + i * 16 + lm) * 32 + quad * 8];
#pragma unroll
        for (int j = 0; j < NJ; j++)
            bfv[j] = *(const bf16x8*)&Bs[(wn + j * 16 + lm) * 32 + quad * 8];
#pragma unroll
        for (int i = 0; i < 4; i++)
#pragma unroll
            for (int j = 0; j < NJ; j++)
                acc[i][j] = __builtin_amdgcn_mfma_f32_16x16x32_bf16(
                    af[i], bfv[j], acc[i][j], 0, 0, 0);
    }

    float bias_f[NJ];
#pragma unroll
    for (int j = 0; j < NJ; j++)
        bias_f[j] = loadDyn(bias, n0 + wn + j * 16 + lm, f);
#pragma unroll
    for (int i = 0; i < 4; i++) {
#pragma unroll
        for (int r = 0; r < 4; r++) {
            int row = m0 + wm + i * 16 + quad * 4 + r;   // C/D: row=quad*4+reg
            size_t rb = (size_t)(moff + row) * N;
#pragma unroll
            for (int j = 0; j < NJ; j++) {
                int col = n0 + wn + j * 16 + lm;          // C/D: col=lane&15
                float vv = acc[i][j][r] + bias_f[j];
                if (ACT == 1) vv = gelu_exact(vv);
                if (RES == 1) vv += b2f(((const u16*)res)[rb + col]);
                if (RES == 2) vv += loadDyn(res, rb + col, f);
                if (STORE == 0) ((u16*)C)[rb + col] = f2b(vv);
                else {
                    if (f) ((float*)C)[rb + col] = vv;
                    else   ((u16*)C)[rb + col] = f2b(vv);
                }
            }
        }
    }
}

// ---------------------------------------------------------------------------
// MFMA masked flash-attention. Block = (h, q-tile 64, b), 4 waves; wave w
// owns query rows w*16..+16. S=QK^T (MFMA), bitmask+online softmax in regs,
// P->LDS->A-frags, O += P V with V staged from the GLOBAL pre-transposed Vt
// (vectorized copies; no per-chunk scalar transpose). o may alias q.
// ---------------------------------------------------------------------------
__global__ __launch_bounds__(256) void attn_mfma_k(
    const u16* q, const u16* __restrict__ k,
    const u16* __restrict__ vt, const u64* __restrict__ mask, u16* o) {
    const int h = blockIdx.x, qg = blockIdx.y, b = blockIdx.z;
    const int q0 = qg * 64;
    const int tid = threadIdx.x;
    const int wave = tid >> 6, lane = tid & 63;
    const int lm = lane & 15, quad = lane >> 4;
    const int wm = wave * 16;
    const int bh = b * Hn + h;

    __shared__ __align__(16) u16 Qs[64 * 72];
    __shared__ __align__(16) u16 Ks[64 * 72];
    __shared__ __align__(16) u16 Vts[64 * 72];   // [dim][key]
    __shared__ __align__(16) u16 Ps[64 * 72];

    {
        const int row = tid >> 2, dc = (tid & 3) * 16;
        const u16* src = q + ((size_t)(b * Nn + q0 + row)) * Dn + h * HDn + dc;
        *(u16x8*)&Qs[row * 72 + dc]     = *(const u16x8*)src;
        *(u16x8*)&Qs[row * 72 + dc + 8] = *(const u16x8*)(src + 8);
    }

    float m_i[4], l_i[4];           // row = wm + quad*4 + r
#pragma unroll
    for (int r = 0; r < 4; r++) { m_i[r] = -3e38f; l_i[r] = 0.f; }
    f32x4 Oacc[4] = {};             // dim = j*16+lm

    for (int kb = 0; kb < Nn / 64; kb++) {
        const int kb0 = kb * 64;
        __syncthreads();   // prior iter's Ks/Vts/Ps reads done; Q staged (kb=0)
        {   // stage K rows + Vt dim-rows (both vectorized)
            const int row = tid >> 2, dc = (tid & 3) * 16;
            const u16* ksrc = k + ((size_t)(b * Nn + kb0 + row)) * Dn + h * HDn + dc;
            *(u16x8*)&Ks[row * 72 + dc]     = *(const u16x8*)ksrc;
            *(u16x8*)&Ks[row * 72 + dc + 8] = *(const u16x8*)(ksrc + 8);
            const int dim = tid >> 2, ks = (tid & 3) * 16;
            const u16* vsrc = vt + ((size_t)bh * HDn + dim) * Nn + kb0 + ks;
            *(u16x8*)&Vts[dim * 72 + ks]     = *(const u16x8*)vsrc;
            *(u16x8*)&Vts[dim * 72 + ks + 8] = *(const u16x8*)(vsrc + 8);
        }
        __syncthreads();
        // S = Q K^T (this wave's 16 rows x 64 keys)
        f32x4 sacc[4] = {};
#pragma unroll
        for (int s = 0; s < 2; s++) {
            bf16x8 aq = *(const bf16x8*)&Qs[(wm + lm) * 72 + s * 32 + quad * 8];
#pragma unroll
            for (int j = 0; j < 4; j++) {
                bf16x8 bk = *(const bf16x8*)&Ks[(j * 16 + lm) * 72 + s * 32 + quad * 8];
                sacc[j] = __builtin_amdgcn_mfma_f32_16x16x32_bf16(aq, bk, sacc[j], 0, 0, 0);
            }
        }
        // bitmask + scale + row max
        float pmax[4];
#pragma unroll
        for (int r = 0; r < 4; r++) {
            const u64 mrow = mask[(size_t)(b * Nn + q0 + wm + quad * 4 + r) * 8 + kb];
            float mx = -3e38f;
#pragma unroll
            for (int j = 0; j < 4; j++) {
                const int bit = (int)((mrow >> (j * 16 + lm)) & 1ull);
                float sc = bit ? sacc[j][r] * 0.125f : -3e38f;
                sacc[j][r] = sc;
                mx = fmaxf(mx, sc);
            }
            mx = fmaxf(mx, __shfl_xor(mx, 1, 64));
            mx = fmaxf(mx, __shfl_xor(mx, 2, 64));
            mx = fmaxf(mx, __shfl_xor(mx, 4, 64));
            mx = fmaxf(mx, __shfl_xor(mx, 8, 64));
            pmax[r] = mx;
        }
        // online update; all-masked rows keep O=0,l=0 (exp(0)=1 harmless)
        float alpha[4];
#pragma unroll
        for (int r = 0; r < 4; r++) {
            float newm = fmaxf(m_i[r], pmax[r]);
            alpha[r] = __expf(m_i[r] - newm);
            m_i[r] = newm;
            float s_ = 0.f;
#pragma unroll
            for (int j = 0; j < 4; j++) {
                float sc = sacc[j][r];
                float p = (sc > -1e30f) ? __expf(sc - newm) : 0.f;
                sacc[j][r] = p;
                s_ += p;
            }
            s_ += __shfl_xor(s_, 1, 64);
            s_ += __shfl_xor(s_, 2, 64);
            s_ += __shfl_xor(s_, 4, 64);
            s_ += __shfl_xor(s_, 8, 64);
            l_i[r] = l_i[r] * alpha[r] + s_;
        }
        // P (C-layout) -> LDS (A-layout source)
#pragma unroll
        for (int r = 0; r < 4; r++)
#pragma unroll
            for (int j = 0; j < 4; j++)
                Ps[(wm + quad * 4 + r) * 72 + j * 16 + lm] = f2b(sacc[j][r]);
#pragma unroll
        for (int j = 0; j < 4; j++)
#pragma unroll
            for (int r = 0; r < 4; r++) Oacc[j][r] *= alpha[r];
        __syncthreads();
        // O += P V   (B from Vt[dim][key]: contiguous b128)
#pragma unroll
        for (int s = 0; s < 2; s++) {
            bf16x8 ap = *(const bf16x8*)&Ps[(wm + lm) * 72 + s * 32 + quad * 8];
#pragma unroll
            for (int j = 0; j < 4; j++) {
                bf16x8 bv = *(const bf16x8*)&Vts[(j * 16 + lm) * 72 + s * 32 + quad * 8];
                Oacc[j] = __builtin_amdgcn_mfma_f32_16x16x32_bf16(ap, bv, Oacc[j], 0, 0, 0);
            }
        }
    }
    float inv[4];
#pragma unroll
    for (int r = 0; r < 4; r++) inv[r] = (l_i[r] > 0.f) ? 1.0f / l_i[r] : 0.f;
#pragma unroll
    for (int r = 0; r < 4; r++) {
        const int row = q0 + wm + quad * 4 + r;
        u16* dst = o + ((size_t)(b * Nn + row)) * Dn + h * HDn;
#pragma unroll
        for (int j = 0; j < 4; j++)
            dst[j * 16 + lm] = f2b(Oacc[j][r] * inv[r]);
    }
}

// ---------------------------------------------------------------------------
extern "C" void kernel_launch(void* const* d_in, const int* in_sizes, int n_in,
                              void* d_out, int out_size, void* d_ws,
                              size_t ws_size, hipStream_t stream) {
    const void* x   = d_in[0];
    const int* adj  = (const int*)d_in[1];
    const void* wq  = d_in[2];
    const void* bq  = d_in[3];
    const void* wk  = d_in[4];
    const void* bk  = d_in[5];
    const void* wv  = d_in[6];
    const void* bv  = d_in[7];
    const void* wo  = d_in[8];
    const void* bo  = d_in[9];
    const void* g1  = d_in[10];
    const void* b1  = d_in[11];
    const void* g2  = d_in[12];
    const void* b2  = d_in[13];
    const void* w1  = d_in[14];
    const void* bf1 = d_in[15];
    const void* w2  = d_in[16];
    const void* bf2 = d_in[17];

    // ---- workspace (~115 MiB) ----
    char* ws = (char*)d_ws;
    size_t off = 0;
    auto alloc = [&](size_t bytes) -> char* {
        char* p = ws + off;
        off += (bytes + 255) & ~(size_t)255;
        return p;
    };
    int* flag = (int*)alloc(4);
    u16* wqT  = (u16*)alloc((size_t)Dn * Dn * 2);
    u16* wkT  = (u16*)alloc((size_t)Dn * Dn * 2);
    u16* wvT  = (u16*)alloc((size_t)Dn * Dn * 2);
    u16* woT  = (u16*)alloc((size_t)Dn * Dn * 2);
    u16* w1T  = (u16*)alloc((size_t)Dn * DFn * 2);
    u16* w2T  = (u16*)alloc((size_t)Dn * DFn * 2);
    u64* maskbuf = (u64*)alloc((size_t)Mn * 8 * 8);        // 1 MB
    const size_t S = (size_t)Mn * Dn * 2;                  // 25.17 MB (256-mult)
    u16* Rh = (u16*)alloc(S);   // LN1-h -> Vt -> LN2-h2
    u16* Rq = (u16*)alloc(S);   // Q -> attn-out -> hidden[lo]
    u16* Rk = (u16*)alloc(S);   // K -> hidden[hi]  (Rq+S == Rk: contiguous)
    u16* Rv = (u16*)alloc(S);   // V -> outb (WO out + residual)

    sniff_k<<<1, 256, 0, stream>>>((const u16*)x, flag);
    mask_build_k<<<Mn * 8 / 256, 256, 0, stream>>>(adj, maskbuf);

    dim3 tb(32, 8);
    transpose_k<<<dim3(Dn / 32, Dn / 32), tb, 0, stream>>>(wq, wqT, Dn, Dn, flag);
    transpose_k<<<dim3(Dn / 32, Dn / 32), tb, 0, stream>>>(wk, wkT, Dn, Dn, flag);
    transpose_k<<<dim3(Dn / 32, Dn / 32), tb, 0, stream>>>(wv, wvT, Dn, Dn, flag);
    transpose_k<<<dim3(Dn / 32, Dn / 32), tb, 0, stream>>>(wo, woT, Dn, Dn, flag);
    transpose_k<<<dim3(DFn / 32, Dn / 32), tb, 0, stream>>>(w1, w1T, Dn, DFn, flag);
    transpose_k<<<dim3(Dn / 32, DFn / 32), tb, 0, stream>>>(w2, w2T, DFn, Dn, flag);

    // LN1: x -> Rh
    ln_k<1><<<Mn / 8, 256, 0, stream>>>(x, g1, b1, Rh, flag);

    // QKV projections (wave-tile 64x128)
    gemm_bt<0, 0, 0, 128><<<dim3(Mn / 128, Dn / 256), 256, 0, stream>>>(
        Rh, wqT, bq, nullptr, Rq, Mn, Dn, Dn, 0, flag);
    gemm_bt<0, 0, 0, 128><<<dim3(Mn / 128, Dn / 256), 256, 0, stream>>>(
        Rh, wkT, bk, nullptr, Rk, Mn, Dn, Dn, 0, flag);
    gemm_bt<0, 0, 0, 128><<<dim3(Mn / 128, Dn / 256), 256, 0, stream>>>(
        Rh, wvT, bv, nullptr, Rv, Mn, Dn, Dn, 0, flag);

    // Vt = V^T per (b,h): Rv -> Rh (Rh dead after QKV)
    vtrans_k<<<dim3(HDn / 32, Nn / 32, Bn * Hn), tb, 0, stream>>>(Rv, Rh);

    // attention: (Rq, Rk, Vt=Rh, mask) -> Rq (in-place over Q)
    attn_mfma_k<<<dim3(Hn, Nn / 64, Bn), 256, 0, stream>>>(Rq, Rk, Rh, maskbuf, Rq);

    // outb = attn @ wo + bo + x -> Rv  (V dead after vtrans)
    gemm_bt<0, 2, 0, 128><<<dim3(Mn / 128, Dn / 256), 256, 0, stream>>>(
        Rq, woT, bo, x, Rv, Mn, Dn, Dn, 0, flag);

    // LN2: Rv -> Rh (Vt dead after attn)
    ln_k<0><<<Mn / 8, 256, 0, stream>>>(Rv, g2, b2, Rh, flag);

    // FFN in 2 M-chunks of 8192; hidden (50.3 MB) spans Rq+Rk
    u16* hidden = Rq;
    for (int c = 0; c < Mn / MCHUNK; c++) {
        gemm_bt<1, 0, 0, 128><<<dim3(MCHUNK / 128, DFn / 256), 256, 0, stream>>>(
            Rh + (size_t)c * MCHUNK * Dn, w1T, bf1, nullptr, hidden,
            MCHUNK, DFn, Dn, 0, flag);
        gemm_bt<0, 1, 1, 64><<<dim3(MCHUNK / 128, Dn / 128), 256, 0, stream>>>(
            hidden, w2T, bf2, Rv, d_out, MCHUNK, Dn, DFn, c * MCHUNK, flag);
    }
}